// Round 1
// baseline (553.564 us; speedup 1.0000x reference)
//
#include <hip/hip_runtime.h>

typedef _Float16 half8  __attribute__((ext_vector_type(8)));
typedef _Float16 half4v __attribute__((ext_vector_type(4)));
typedef float    floatx4 __attribute__((ext_vector_type(4)));

#define GLD_LDS16(g, l)                                                        \
  __builtin_amdgcn_global_load_lds(                                            \
      (const __attribute__((address_space(1))) void*)(g),                      \
      (__attribute__((address_space(3))) void*)(l), 16, 0, 0)

// ---------------------------------------------------------------------------
// Generic C = A * B^T GEMM, A:[M][K] lda, B:[N][K] ldb, f16 inputs, fp32 acc.
// 128x128 block tile, BK=32, 256 threads (4 waves, 2x2 of 64x64 per wave),
// mfma_f32_16x16x32_f16, global_load_lds width-16 staging (m97 structure).
// EPI: 0 = f16 store + bias (QK proj), 1 = f16 transposed store per batch
//      (V^T) + bias, 2 = f16 store * scale (scores), 3 = fp32 store (output).
// ---------------------------------------------------------------------------
template <int EPI>
__global__ __launch_bounds__(256) void gemm_bt(
    const _Float16* __restrict__ A, const _Float16* __restrict__ B,
    void* __restrict__ Cv, int lda, int ldb, int ldc, int kdim,
    long long sAz, long long sBz, long long sCz,
    const float* __restrict__ bias0, const float* __restrict__ bias1,
    float scale) {
  __shared__ _Float16 sA[128 * 32];
  __shared__ _Float16 sB[128 * 32];

  const int z = blockIdx.z;
  A += (size_t)z * sAz;
  B += (size_t)z * sBz;

  const int tid = threadIdx.x;
  const int wid = tid >> 6;
  const int lane = tid & 63;
  const int m0 = blockIdx.y * 128;
  const int n0 = blockIdx.x * 128;

  const int wm = (wid & 1) * 64;  // wave m offset within tile
  const int wn = (wid >> 1) * 64; // wave n offset within tile
  const int lr = lane & 15;       // fragment row/col
  const int lk = lane >> 4;       // k quad

  floatx4 acc[4][4];
#pragma unroll
  for (int i = 0; i < 4; ++i)
#pragma unroll
    for (int j = 0; j < 4; ++j)
#pragma unroll
      for (int r = 0; r < 4; ++r) acc[i][j][r] = 0.f;

  for (int k0 = 0; k0 < kdim; k0 += 32) {
    // Stage A,B tiles: 128 rows x 32 f16 = 512 chunks of 16B each, 2 calls
    // per thread per operand. LDS dest = wave-uniform base + lane*16.
#pragma unroll
    for (int j = 0; j < 2; ++j) {
      const int c = j * 256 + wid * 64 + lane;      // chunk id (row=c>>2, kc=c&3)
      const int ub = (j * 256 + wid * 64) * 8;      // uniform LDS element base
      const _Float16* ga = A + (size_t)(m0 + (c >> 2)) * lda + k0 + (c & 3) * 8;
      GLD_LDS16(ga, &sA[ub]);
      const _Float16* gb = B + (size_t)(n0 + (c >> 2)) * ldb + k0 + (c & 3) * 8;
      GLD_LDS16(gb, &sB[ub]);
    }
    __syncthreads();  // drains vmcnt(0): global_load_lds complete

    half8 af[4], bf[4];
#pragma unroll
    for (int t = 0; t < 4; ++t) {
      af[t] = *(const half8*)&sA[(wm + t * 16 + lr) * 32 + lk * 8];
      bf[t] = *(const half8*)&sB[(wn + t * 16 + lr) * 32 + lk * 8];
    }
#pragma unroll
    for (int mt = 0; mt < 4; ++mt)
#pragma unroll
      for (int nt = 0; nt < 4; ++nt)
        acc[mt][nt] = __builtin_amdgcn_mfma_f32_16x16x32_f16(
            af[mt], bf[nt], acc[mt][nt], 0, 0, 0);
    __syncthreads();  // protect LDS before next stage
  }

  const float* bias = nullptr;
  if (EPI == 0 || EPI == 1) bias = (z == 0) ? bias0 : bias1;

  // C/D layout (16x16): col = lane&15, row = (lane>>4)*4 + reg  [m89/m91]
#pragma unroll
  for (int mt = 0; mt < 4; ++mt) {
#pragma unroll
    for (int nt = 0; nt < 4; ++nt) {
#pragma unroll
      for (int r = 0; r < 4; ++r) {
        const int gm = m0 + wm + mt * 16 + lk * 4 + r;
        const int gn = n0 + wn + nt * 16 + lr;
        float v = acc[mt][nt][r];
        if (EPI == 0) {
          v += bias[gn];
          ((_Float16*)Cv)[(size_t)z * sCz + (size_t)gm * ldc + gn] = (_Float16)v;
        } else if (EPI == 1) {
          v += bias[gn];
          const int b = gm >> 11, s = gm & 2047;  // token -> (batch, seq)
          ((_Float16*)Cv)[(size_t)b * 2097152 + (size_t)gn * 2048 + s] =
              (_Float16)v;
        } else if (EPI == 2) {
          ((_Float16*)Cv)[(size_t)z * sCz + (size_t)gm * ldc + gn] =
              (_Float16)(v * scale);
        } else {
          ((float*)Cv)[(size_t)z * sCz + (size_t)gm * ldc + gn] = v;
        }
      }
    }
  }
}

// ---------------------------------------------------------------------------
// fp32 -> f16 convert, 4 elements/thread
// ---------------------------------------------------------------------------
__global__ __launch_bounds__(256) void cvt_x(const float* __restrict__ x,
                                             _Float16* __restrict__ y) {
  const int i = blockIdx.x * 256 + threadIdx.x;
  const float4 v = ((const float4*)x)[i];
  half4v h;
  h[0] = (_Float16)v.x;
  h[1] = (_Float16)v.y;
  h[2] = (_Float16)v.z;
  h[3] = (_Float16)v.w;
  ((half4v*)y)[i] = h;
}

// ---------------------------------------------------------------------------
// W[h][d] fp32 -> Wt[d][h] f16, 32x32 LDS tile transpose, z selects matrix
// ---------------------------------------------------------------------------
__global__ __launch_bounds__(256) void transpose_w(
    const float* __restrict__ W0, const float* __restrict__ W1,
    const float* __restrict__ W2, _Float16* __restrict__ Wt) {
  __shared__ float tile[32][33];
  const float* W = blockIdx.z == 0 ? W0 : (blockIdx.z == 1 ? W1 : W2);
  _Float16* T = Wt + (size_t)blockIdx.z * 1048576;
  const int d0 = blockIdx.x * 32, h0 = blockIdx.y * 32;
  const int tx = threadIdx.x, ty = threadIdx.y;
#pragma unroll
  for (int i = 0; i < 4; ++i)
    tile[ty + i * 8][tx] = W[(size_t)(h0 + ty + i * 8) * 1024 + d0 + tx];
  __syncthreads();
#pragma unroll
  for (int i = 0; i < 4; ++i)
    T[(size_t)(d0 + ty + i * 8) * 1024 + h0 + tx] =
        (_Float16)tile[tx][ty + i * 8];
}

// ---------------------------------------------------------------------------
// In-place row softmax over 2048 f16 scores, one block (256 thr) per row
// ---------------------------------------------------------------------------
__global__ __launch_bounds__(256) void softmax_rows(_Float16* __restrict__ S) {
  __shared__ float red[8];
  _Float16* p = S + (size_t)blockIdx.x * 2048;
  const int tid = threadIdx.x;
  const int wid = tid >> 6, lane = tid & 63;

  half8 hv = *(const half8*)&p[tid * 8];
  float f[8];
#pragma unroll
  for (int i = 0; i < 8; ++i) f[i] = (float)hv[i];

  float m = f[0];
#pragma unroll
  for (int i = 1; i < 8; ++i) m = fmaxf(m, f[i]);
#pragma unroll
  for (int o = 32; o > 0; o >>= 1) m = fmaxf(m, __shfl_xor(m, o));
  if (lane == 0) red[wid] = m;
  __syncthreads();
  m = fmaxf(fmaxf(red[0], red[1]), fmaxf(red[2], red[3]));

  float s = 0.f;
#pragma unroll
  for (int i = 0; i < 8; ++i) {
    f[i] = exp2f((f[i] - m) * 1.44269504088896f);
    s += f[i];
  }
#pragma unroll
  for (int o = 32; o > 0; o >>= 1) s += __shfl_xor(s, o);
  if (lane == 0) red[4 + wid] = s;
  __syncthreads();
  s = red[4] + red[5] + red[6] + red[7];
  const float inv = 1.f / s;

  half8 out;
#pragma unroll
  for (int i = 0; i < 8; ++i) out[i] = (_Float16)(f[i] * inv);
  *(half8*)&p[tid * 8] = out;
}

// ---------------------------------------------------------------------------
// inputs: x[8,2048,1024] f32, Wq[1024,1024], bq[1024], Wk, bk, Wv, bv
// out: [8,2048,1024] f32
// ws layout (bytes): xb f16 @0 (32M), Wt f16 @32M (6M), Q f16 @38M (32M),
//   K f16 @70M (32M), Vt f16 [b][d][s] @102M (32M), S/P f16 @134M (64M)
//   total 207,618,048 B
// ---------------------------------------------------------------------------
extern "C" void kernel_launch(void* const* d_in, const int* in_sizes, int n_in,
                              void* d_out, int out_size, void* d_ws,
                              size_t ws_size, hipStream_t stream) {
  const float* x = (const float*)d_in[0];
  const float* Wq = (const float*)d_in[1];
  const float* bq = (const float*)d_in[2];
  const float* Wk = (const float*)d_in[3];
  const float* bk = (const float*)d_in[4];
  const float* Wv = (const float*)d_in[5];
  const float* bv = (const float*)d_in[6];
  float* out = (float*)d_out;

  char* w = (char*)d_ws;
  _Float16* xb = (_Float16*)(w);
  _Float16* Wt = (_Float16*)(w + 33554432);
  _Float16* Q  = (_Float16*)(w + 39845888);
  _Float16* K  = (_Float16*)(w + 73400320);
  _Float16* Vt = (_Float16*)(w + 106954752);
  _Float16* S  = (_Float16*)(w + 140509184);

  // 1) x -> f16 (16,777,216 elems / 4 per thread)
  cvt_x<<<16384, 256, 0, stream>>>(x, xb);
  // 2) W -> Wt[d][h] f16
  transpose_w<<<dim3(32, 32, 3), dim3(32, 8), 0, stream>>>(Wq, Wk, Wv, Wt);
  // 3) Q,K = xb @ Wt^T (+bias); M=16384, N=1024, K=1024; z in {Q,K}
  gemm_bt<0><<<dim3(8, 128, 2), 256, 0, stream>>>(
      xb, Wt, Q, 1024, 1024, 1024, 1024, 0LL, 1048576LL, 16777216LL, bq, bk,
      1.f);
  // 4) V^T[b][d][s] = (xb @ Wv^T + bv) transposed per batch
  gemm_bt<1><<<dim3(8, 128, 1), 256, 0, stream>>>(
      xb, Wt + 2097152, Vt, 1024, 1024, 0, 1024, 0LL, 0LL, 0LL, bv, bv, 1.f);
  // 5) S = (Q @ K^T) * 1/32 per batch; M=N=2048, K=1024
  gemm_bt<2><<<dim3(16, 16, 8), 256, 0, stream>>>(
      Q, K, S, 1024, 1024, 2048, 1024, 2097152LL, 2097152LL, 4194304LL,
      nullptr, nullptr, 0.03125f);
  // 6) in-place row softmax (8*2048 rows x 2048)
  softmax_rows<<<16384, 256, 0, stream>>>(S);
  // 7) out = P @ V = P @ (Vt)^T per batch; M=2048, N=1024, K=2048; fp32 out
  gemm_bt<3><<<dim3(8, 16, 8), 256, 0, stream>>>(
      S, Vt, out, 2048, 2048, 1024, 2048, 4194304LL, 2097152LL, 2097152LL,
      nullptr, nullptr, 1.f);

  (void)in_sizes;
  (void)n_in;
  (void)out_size;
  (void)ws_size;
}

// Round 2
// 488.904 us; speedup vs baseline: 1.1323x; 1.1323x over previous
//
#include <hip/hip_runtime.h>

typedef _Float16 half8  __attribute__((ext_vector_type(8)));
typedef _Float16 half4v __attribute__((ext_vector_type(4)));
typedef float    floatx4 __attribute__((ext_vector_type(4)));

#define GLD_LDS16(g, l)                                                        \
  __builtin_amdgcn_global_load_lds(                                            \
      (const __attribute__((address_space(1))) void*)(g),                      \
      (__attribute__((address_space(3))) void*)(l), 16, 0, 0)

// ---------------------------------------------------------------------------
// Generic C = A * B^T GEMM, A:[M][K] lda, B:[N][K] ldb, f16 in, fp32 acc.
// 128x128 block tile, BK=64 (32 KB LDS), 256 threads (4 waves, 64x64/wave),
// mfma_f32_16x16x32_f16, global_load_lds width-16 staging.
// LDS layout: chunk (row, kc) lives at slot row*8 + (kc ^ (row&7)); the XOR
// swizzle keeps fragment reads spread over all 8 bank groups (naive BK=64
// layout would put 16 lanes on one group) while global_load_lds's
// lane-contiguous LDS dest is preserved (lanes permute WHICH chunk of the
// same 128B global row segment they fetch -> coalescing intact).
// EPI: 0 = merged QKV projection (z=0 Q, z=1 K row-store f16 +bias;
//          z=2 V^T per-batch transposed store +bias)
//      2 = f16 store * scale (scores), 3 = fp32 store (output).
// ---------------------------------------------------------------------------
template <int EPI>
__global__ __launch_bounds__(256) void gemm_bt(
    const _Float16* __restrict__ A, const _Float16* __restrict__ B,
    void* __restrict__ Cv, void* __restrict__ Cv2, int lda, int ldb, int ldc,
    int kdim, long long sAz, long long sBz, long long sCz,
    const float* __restrict__ b0, const float* __restrict__ b1,
    const float* __restrict__ b2, float scale) {
  __shared__ _Float16 sA[128 * 64];
  __shared__ _Float16 sB[128 * 64];

  const int z = blockIdx.z;
  A += (size_t)z * sAz;
  B += (size_t)z * sBz;

  const int tid = threadIdx.x;
  const int wid = tid >> 6;
  const int lane = tid & 63;
  const int m0 = blockIdx.y * 128;
  const int n0 = blockIdx.x * 128;

  const int wm = (wid & 1) * 64;  // wave m offset within tile
  const int wn = (wid >> 1) * 64; // wave n offset within tile
  const int lr = lane & 15;       // fragment row/col
  const int lk = lane >> 4;       // k quad

  floatx4 acc[4][4];
#pragma unroll
  for (int i = 0; i < 4; ++i)
#pragma unroll
    for (int j = 0; j < 4; ++j)
#pragma unroll
      for (int r = 0; r < 4; ++r) acc[i][j][r] = 0.f;

  for (int k0 = 0; k0 < kdim; k0 += 64) {
    // Stage 128 rows x 64 f16 per operand = 1024 16B chunks, 4 calls/thread.
#pragma unroll
    for (int j = 0; j < 4; ++j) {
      const int s = j * 256 + wid * 64 + lane;  // LDS chunk slot (contiguous)
      const int ub = (j * 256 + wid * 64) * 8;  // wave-uniform LDS elem base
      const int row = s >> 3;
      const int kc = (s & 7) ^ (row & 7);       // swizzled global chunk
      GLD_LDS16(A + (size_t)(m0 + row) * lda + k0 + kc * 8, &sA[ub]);
      GLD_LDS16(B + (size_t)(n0 + row) * ldb + k0 + kc * 8, &sB[ub]);
    }
    __syncthreads();  // drains vmcnt(0): global_load_lds complete

#pragma unroll
    for (int ks = 0; ks < 2; ++ks) {
      half8 af[4], bf[4];
#pragma unroll
      for (int t = 0; t < 4; ++t) {
        const int ra = wm + t * 16 + lr;
        const int kcl = ks * 4 + lk;
        af[t] = *(const half8*)&sA[(ra * 8 + (kcl ^ (ra & 7))) * 8];
        const int rb = wn + t * 16 + lr;
        bf[t] = *(const half8*)&sB[(rb * 8 + (kcl ^ (rb & 7))) * 8];
      }
#pragma unroll
      for (int mt = 0; mt < 4; ++mt)
#pragma unroll
        for (int nt = 0; nt < 4; ++nt)
          acc[mt][nt] = __builtin_amdgcn_mfma_f32_16x16x32_f16(
              af[mt], bf[nt], acc[mt][nt], 0, 0, 0);
    }
    __syncthreads();  // protect LDS before next stage
  }

  const float* bias = nullptr;
  if (EPI == 0) bias = (z == 0) ? b0 : ((z == 1) ? b1 : b2);

  // C/D layout (16x16): col = lane&15, row = (lane>>4)*4 + reg  [m89/m91]
#pragma unroll
  for (int mt = 0; mt < 4; ++mt) {
#pragma unroll
    for (int nt = 0; nt < 4; ++nt) {
#pragma unroll
      for (int r = 0; r < 4; ++r) {
        const int gm = m0 + wm + mt * 16 + lk * 4 + r;
        const int gn = n0 + wn + nt * 16 + lr;
        float v = acc[mt][nt][r];
        if (EPI == 0) {
          v += bias[gn];
          if (z < 2) {  // Q / K row-major f16
            ((_Float16*)Cv)[(size_t)z * 16777216 + (size_t)gm * 1024 + gn] =
                (_Float16)v;
          } else {  // V^T[b][d][s] f16
            const int b = gm >> 11, sseq = gm & 2047;
            ((_Float16*)Cv2)[(size_t)b * 2097152 + (size_t)gn * 2048 + sseq] =
                (_Float16)v;
          }
        } else if (EPI == 2) {
          ((_Float16*)Cv)[(size_t)z * sCz + (size_t)gm * ldc + gn] =
              (_Float16)(v * scale);
        } else {
          ((float*)Cv)[(size_t)z * sCz + (size_t)gm * ldc + gn] = v;
        }
      }
    }
  }
}

// ---------------------------------------------------------------------------
// fp32 -> f16 convert, 4 elements/thread
// ---------------------------------------------------------------------------
__global__ __launch_bounds__(256) void cvt_x(const float* __restrict__ x,
                                             _Float16* __restrict__ y) {
  const int i = blockIdx.x * 256 + threadIdx.x;
  const float4 v = ((const float4*)x)[i];
  half4v h;
  h[0] = (_Float16)v.x;
  h[1] = (_Float16)v.y;
  h[2] = (_Float16)v.z;
  h[3] = (_Float16)v.w;
  ((half4v*)y)[i] = h;
}

// ---------------------------------------------------------------------------
// W[h][d] fp32 -> Wt[d][h] f16, 32x32 LDS tile transpose, z selects matrix
// ---------------------------------------------------------------------------
__global__ __launch_bounds__(256) void transpose_w(
    const float* __restrict__ W0, const float* __restrict__ W1,
    const float* __restrict__ W2, _Float16* __restrict__ Wt) {
  __shared__ float tile[32][33];
  const float* W = blockIdx.z == 0 ? W0 : (blockIdx.z == 1 ? W1 : W2);
  _Float16* T = Wt + (size_t)blockIdx.z * 1048576;
  const int d0 = blockIdx.x * 32, h0 = blockIdx.y * 32;
  const int tx = threadIdx.x, ty = threadIdx.y;
#pragma unroll
  for (int i = 0; i < 4; ++i)
    tile[ty + i * 8][tx] = W[(size_t)(h0 + ty + i * 8) * 1024 + d0 + tx];
  __syncthreads();
#pragma unroll
  for (int i = 0; i < 4; ++i)
    T[(size_t)(d0 + ty + i * 8) * 1024 + h0 + tx] =
        (_Float16)tile[tx][ty + i * 8];
}

// ---------------------------------------------------------------------------
// In-place row softmax over 2048 f16 scores, one block (256 thr) per row
// ---------------------------------------------------------------------------
__global__ __launch_bounds__(256) void softmax_rows(_Float16* __restrict__ S) {
  __shared__ float red[8];
  _Float16* p = S + (size_t)blockIdx.x * 2048;
  const int tid = threadIdx.x;
  const int wid = tid >> 6, lane = tid & 63;

  half8 hv = *(const half8*)&p[tid * 8];
  float f[8];
#pragma unroll
  for (int i = 0; i < 8; ++i) f[i] = (float)hv[i];

  float m = f[0];
#pragma unroll
  for (int i = 1; i < 8; ++i) m = fmaxf(m, f[i]);
#pragma unroll
  for (int o = 32; o > 0; o >>= 1) m = fmaxf(m, __shfl_xor(m, o));
  if (lane == 0) red[wid] = m;
  __syncthreads();
  m = fmaxf(fmaxf(red[0], red[1]), fmaxf(red[2], red[3]));

  float s = 0.f;
#pragma unroll
  for (int i = 0; i < 8; ++i) {
    f[i] = exp2f((f[i] - m) * 1.44269504088896f);
    s += f[i];
  }
#pragma unroll
  for (int o = 32; o > 0; o >>= 1) s += __shfl_xor(s, o);
  if (lane == 0) red[4 + wid] = s;
  __syncthreads();
  s = red[4] + red[5] + red[6] + red[7];
  const float inv = 1.f / s;

  half8 out;
#pragma unroll
  for (int i = 0; i < 8; ++i) out[i] = (_Float16)(f[i] * inv);
  *(half8*)&p[tid * 8] = out;
}

// ---------------------------------------------------------------------------
// inputs: x[8,2048,1024] f32, Wq[1024,1024], bq[1024], Wk, bk, Wv, bv
// out: [8,2048,1024] f32
// ws layout (bytes): xb f16 @0 (32M), Wt f16 @32M (6M), Q,K f16 @38M (64M),
//   Vt f16 [b][d][s] @102M (32M), S/P f16 @134M (64M) -> total ~198M
// ---------------------------------------------------------------------------
extern "C" void kernel_launch(void* const* d_in, const int* in_sizes, int n_in,
                              void* d_out, int out_size, void* d_ws,
                              size_t ws_size, hipStream_t stream) {
  const float* x = (const float*)d_in[0];
  const float* Wq = (const float*)d_in[1];
  const float* bq = (const float*)d_in[2];
  const float* Wk = (const float*)d_in[3];
  const float* bk = (const float*)d_in[4];
  const float* Wv = (const float*)d_in[5];
  const float* bv = (const float*)d_in[6];
  float* out = (float*)d_out;

  char* w = (char*)d_ws;
  _Float16* xb = (_Float16*)(w);
  _Float16* Wt = (_Float16*)(w + 33554432);
  _Float16* QK = (_Float16*)(w + 39845888);   // Q then K, 16777216 elems each
  _Float16* Vt = (_Float16*)(w + 106954752);
  _Float16* S  = (_Float16*)(w + 140509184);

  // 1) x -> f16
  cvt_x<<<16384, 256, 0, stream>>>(x, xb);
  // 2) W -> Wt[d][h] f16
  transpose_w<<<dim3(32, 32, 3), dim3(32, 8), 0, stream>>>(Wq, Wk, Wv, Wt);
  // 3) merged QKV projection: z=0 Q, z=1 K, z=2 V^T; M=16384,N=1024,K=1024
  gemm_bt<0><<<dim3(8, 128, 3), 256, 0, stream>>>(
      xb, Wt, QK, Vt, 1024, 1024, 1024, 1024, 0LL, 1048576LL, 0LL, bq, bk, bv,
      1.f);
  // 4) S = (Q @ K^T) * 1/32 per batch; M=N=2048, K=1024
  gemm_bt<2><<<dim3(16, 16, 8), 256, 0, stream>>>(
      QK, QK + 16777216, S, nullptr, 1024, 1024, 2048, 1024, 2097152LL,
      2097152LL, 4194304LL, nullptr, nullptr, nullptr, 0.03125f);
  // 5) in-place row softmax (8*2048 rows x 2048)
  softmax_rows<<<16384, 256, 0, stream>>>(S);
  // 6) out = P @ (Vt)^T per batch; M=2048, N=1024, K=2048; fp32 out
  gemm_bt<3><<<dim3(8, 16, 8), 256, 0, stream>>>(
      S, Vt, out, nullptr, 2048, 2048, 1024, 2048, 4194304LL, 2097152LL,
      2097152LL, nullptr, nullptr, nullptr, 1.f);

  (void)in_sizes;
  (void)n_in;
  (void)out_size;
  (void)ws_size;
}